// Round 2
// baseline (428.570 us; speedup 1.0000x reference)
//
#include <hip/hip_runtime.h>

typedef unsigned short u16;
typedef short bf16x8 __attribute__((ext_vector_type(8)));
typedef float f32x4  __attribute__((ext_vector_type(4)));

#define NN 64
#define DD 256
#define LL 4096
#define KK 64
#define CHUNK 1024
#define LS 64
#define NSUB 16

__device__ __forceinline__ u16 f2bf(float f) {
  union { float f; unsigned int i; } v; v.f = f;
  unsigned int u = v.i;
  return (u16)((u + 0x7FFFu + ((u >> 16) & 1u)) >> 16);  // RNE
}
__device__ __forceinline__ float bf2f(u16 u) {
  union { unsigned int i; float f; } v; v.i = ((unsigned int)u) << 16; return v.f;
}

__global__ void zero_ws_kernel(float* __restrict__ p, int n4) {
  int i = blockIdx.x * 256 + threadIdx.x;
  if (i < n4) ((f32x4*)p)[i] = (f32x4){0.f, 0.f, 0.f, 0.f};
}

// ---------------------------------------------------------------------------
// Main fused kernel. Inputs fp32; MFMA in bf16 with fp32 accumulation.
// Per (n, l-chunk of 1024): normalize descriptors (fp32), logits via MFMA,
// softmax over K, aggregation GEMM via MFMA, atomic accumulate to fp32 ws.
// LDS swizzle: a row of 16B chunks; chunk c of row r stored at c ^ (r & mask).
// ---------------------------------------------------------------------------
__global__ __launch_bounds__(256, 1) void netvlad_main(
    const float* __restrict__ xg, const float* __restrict__ wg,
    float* __restrict__ Sg, float* __restrict__ Ag) {
  __shared__ u16  x_dl[DD * LS];    // xn, [d][l] (8 chunks/row, swizzled)
  __shared__ u16  x_ld[LS * DD];    // xn^T, [l][d] (32 chunks/row, swizzled)
  __shared__ float lg[LS * KK];     // logits, [l][k] fp32 (16 chunks/row)
  __shared__ u16  akl[KK * LS];     // softmax a, [k][l] (8 chunks/row)
  __shared__ float pn[32 * LS];     // norm partials [dblk][l]
  __shared__ float rno[LS];         // 1/||x_l||

  const int tid  = threadIdx.x;
  const int w    = tid >> 6;        // wave 0..3
  const int lane = tid & 63;
  const int quad = lane >> 4;
  const int l15  = lane & 15;
  const int dblk = tid >> 3;        // 0..31
  const int lblk = tid & 7;         // 0..7
  const int n    = blockIdx.x >> 2;
  const int ch   = blockIdx.x & 3;

  // Preload W fragments for GEMM1 (wave w owns k-rows w*16..w*16+15).
  // A-frag (16x16x32): A[m=lane&15][kred=quad*8+j]
  bf16x8 aw[8];
  {
    const float* wp = wg + (w * 16 + l15) * DD + quad * 8;
#pragma unroll
    for (int s = 0; s < 8; ++s) {
      f32x4 wa = *(const f32x4*)(wp + s * 32);
      f32x4 wb = *(const f32x4*)(wp + s * 32 + 4);
      bf16x8 t;
#pragma unroll
      for (int j = 0; j < 4; ++j) { t[j] = (short)f2bf(wa[j]); t[j + 4] = (short)f2bf(wb[j]); }
      aw[s] = t;
    }
  }

  f32x4 acc2[16];                   // S-accumulator: wave w = k-tile w, 16 d-tiles
#pragma unroll
  for (int i = 0; i < 16; ++i) acc2[i] = (f32x4){0.f, 0.f, 0.f, 0.f};
  float regA = 0.f;                 // A_k partial (tid<64 -> k=tid)

  const float* xbase = xg + (size_t)n * DD * LL + (size_t)ch * CHUNK;

  // Stage sub-tile 0 into registers: thread owns an 8d x 8l block (fp32).
  f32x4 ga[8], gb[8];
#pragma unroll
  for (int r = 0; r < 8; ++r) {
    const float* p = xbase + (size_t)(dblk * 8 + r) * LL + lblk * 8;
    ga[r] = *(const f32x4*)p;
    gb[r] = *(const f32x4*)(p + 4);
  }

  for (int it = 0; it < NSUB; ++it) {
    // ---- descriptor norms (over d) from registers, fp32
    float pj[8];
#pragma unroll
    for (int j = 0; j < 8; ++j) pj[j] = 0.f;
#pragma unroll
    for (int r = 0; r < 8; ++r)
#pragma unroll
      for (int j = 0; j < 4; ++j) {
        pj[j]     += ga[r][j] * ga[r][j];
        pj[j + 4] += gb[r][j] * gb[r][j];
      }
    *(f32x4*)&pn[dblk * 64 + lblk * 8]     = (f32x4){pj[0], pj[1], pj[2], pj[3]};
    *(f32x4*)&pn[dblk * 64 + lblk * 8 + 4] = (f32x4){pj[4], pj[5], pj[6], pj[7]};
    __syncthreads();
    if (tid < 64) {
      float s = 0.f;
#pragma unroll
      for (int db = 0; db < 32; ++db) s += pn[db * 64 + tid];
      rno[tid] = 1.f / fmaxf(sqrtf(s), 1e-12f);
    }
    __syncthreads();

    // ---- scale to unit descriptors (fp32 * fp32), quantize to bf16, both layouts
    float rn[8];
#pragma unroll
    for (int j = 0; j < 8; ++j) rn[j] = rno[lblk * 8 + j];
    u16 xn[8][8];
#pragma unroll
    for (int r = 0; r < 8; ++r)
#pragma unroll
      for (int j = 0; j < 4; ++j) {
        xn[r][j]     = f2bf(ga[r][j] * rn[j]);
        xn[r][j + 4] = f2bf(gb[r][j] * rn[j + 4]);
      }
#pragma unroll
    for (int r = 0; r < 8; ++r) {          // [d][l]: row d=dblk*8+r (d&7==r), chunk lblk
      bf16x8 row;
#pragma unroll
      for (int j = 0; j < 8; ++j) row[j] = (short)xn[r][j];
      *(bf16x8*)&x_dl[(dblk * 8 + r) * 64 + ((lblk ^ r) * 8)] = row;
    }
#pragma unroll
    for (int j = 0; j < 8; ++j) {          // [l][d]: row lam, chunk dblk (reg transpose)
      bf16x8 col;
#pragma unroll
      for (int r = 0; r < 8; ++r) col[r] = (short)xn[r][j];
      int lam = lblk * 8 + j;
      *(bf16x8*)&x_ld[lam * 256 + ((dblk ^ (lam & 31)) * 8)] = col;
    }

    // ---- prefetch next sub-tile (hidden under the GEMMs)
    if (it + 1 < NSUB) {
      const float* p = xbase + (it + 1) * LS;
#pragma unroll
      for (int r = 0; r < 8; ++r) {
        const float* q = p + (size_t)(dblk * 8 + r) * LL + lblk * 8;
        ga[r] = *(const f32x4*)q;
        gb[r] = *(const f32x4*)(q + 4);
      }
    }
    __syncthreads();

    // ---- GEMM1: logits[k,l] = sum_d W[k,d]*xn[d,l]; wave w = k-tile w
    f32x4 acc1[4];
#pragma unroll
    for (int lt = 0; lt < 4; ++lt) acc1[lt] = (f32x4){0.f, 0.f, 0.f, 0.f};
#pragma unroll
    for (int s = 0; s < 8; ++s) {
#pragma unroll
      for (int lt = 0; lt < 4; ++lt) {
        int lam = lt * 16 + l15;  // B[kred=d][n=l]: row lam of x_ld, d-chunk s*4+quad
        bf16x8 b = *(const bf16x8*)&x_ld[lam * 256 + (((s * 4 + quad) ^ (lam & 31)) * 8)];
        acc1[lt] = __builtin_amdgcn_mfma_f32_16x16x32_bf16(aw[s], b, acc1[lt], 0, 0, 0);
      }
    }
    // C layout: k = w*16 + quad*4 + reg, l = lt*16 + l15 -> lg[l][k], 4 consec k = chunk
#pragma unroll
    for (int lt = 0; lt < 4; ++lt) {
      int lam = lt * 16 + l15;
      *(f32x4*)&lg[lam * 64 + (((w * 4 + quad) ^ (lam & 15)) * 4)] = acc1[lt];
    }
    __syncthreads();

    // ---- softmax over k per column (wave 0; thread = column)
    if (tid < 64) {
      const int lam = tid, sw = lam & 15;
      float mx = -1e30f;
#pragma unroll
      for (int c = 0; c < 16; ++c) {
        f32x4 v = *(const f32x4*)&lg[lam * 64 + ((c ^ sw) * 4)];
        mx = fmaxf(mx, fmaxf(fmaxf(v[0], v[1]), fmaxf(v[2], v[3])));
      }
      float sum = 0.f;
#pragma unroll
      for (int c = 0; c < 16; ++c) {
        f32x4 v = *(const f32x4*)&lg[lam * 64 + ((c ^ sw) * 4)];
#pragma unroll
        for (int i = 0; i < 4; ++i) sum += __expf(v[i] - mx);
      }
      float rs = 1.f / sum;
#pragma unroll
      for (int c = 0; c < 16; ++c) {
        f32x4 v = *(const f32x4*)&lg[lam * 64 + ((c ^ sw) * 4)];
#pragma unroll
        for (int i = 0; i < 4; ++i) {
          int k = c * 4 + i;   // position (c^sw) holds logical chunk c
          float a = __expf(v[i] - mx) * rs;
          akl[k * 64 + (((lam >> 3) ^ (k & 7)) * 8) + (lam & 7)] = f2bf(a);
        }
      }
    }
    __syncthreads();

    // ---- GEMM2: S[k,d] += sum_l a[k,l]*xn[d,l]; wave w = k-tile w
#pragma unroll
    for (int s = 0; s < 2; ++s) {
      int kk = w * 16 + l15;  // A[m=k][kred=l]
      bf16x8 aA = *(const bf16x8*)&akl[kk * 64 + (((s * 4 + quad) ^ (kk & 7)) * 8)];
#pragma unroll
      for (int dt = 0; dt < 16; ++dt) {
        int d = dt * 16 + l15;  // B[kred=l][n=d] = xn[d][l]: row d of x_dl
        bf16x8 bX = *(const bf16x8*)&x_dl[d * 64 + (((s * 4 + quad) ^ (d & 7)) * 8)];
        acc2[dt] = __builtin_amdgcn_mfma_f32_16x16x32_bf16(aA, bX, acc2[dt], 0, 0, 0);
      }
    }
    // ---- A_k partial sums (wave 0; thread = k-row of akl)
    if (tid < 64) {
      const int k = tid;
#pragma unroll
      for (int c = 0; c < 8; ++c) {
        bf16x8 v = *(const bf16x8*)&akl[k * 64 + ((c ^ (k & 7)) * 8)];
#pragma unroll
        for (int j = 0; j < 8; ++j) regA += bf2f((u16)v[j]);
      }
    }
    __syncthreads();
  }

  // ---- epilogue: accumulate into global S[n,k,d], A[n,k]
  float* Sn = Sg + ((size_t)n * KK * DD);
#pragma unroll
  for (int dt = 0; dt < 16; ++dt) {
#pragma unroll
    for (int r = 0; r < 4; ++r) {
      int k = w * 16 + quad * 4 + r;
      int d = dt * 16 + l15;
      atomicAdd(&Sn[k * DD + d], acc2[dt][r]);
    }
  }
  if (tid < 64) atomicAdd(&Ag[n * KK + tid], regA);
}

// ---------------------------------------------------------------------------
// Finalize: vlad = S - A*c, intra-norm over d, global norm, fp32 store.
// One block per n.
// ---------------------------------------------------------------------------
__global__ __launch_bounds__(256, 1) void netvlad_fin(
    const float* __restrict__ Sg, const float* __restrict__ Ag,
    const float* __restrict__ cg, float* __restrict__ outg) {
  __shared__ float red[256];
  __shared__ float tot[64];
  __shared__ float rk[64];
  __shared__ float gsh;
  const int n = blockIdx.x, tid = threadIdx.x;
  const int k = tid >> 2, part = tid & 3;
  const float* Sp = Sg + ((size_t)n * KK + k) * DD + part * 64;
  const float* cp = cg + k * DD + part * 64;
  const float Ak  = Ag[n * KK + k];
  float v[64];
  float s2 = 0.f;
#pragma unroll
  for (int j = 0; j < 64; ++j) {
    float t = Sp[j] - Ak * cp[j];
    v[j] = t;
    s2 += t * t;
  }
  red[tid] = s2;
  __syncthreads();
  if (tid < 64) {
    float s = red[tid * 4] + red[tid * 4 + 1] + red[tid * 4 + 2] + red[tid * 4 + 3];
    float r = 1.f / fmaxf(sqrtf(s), 1e-12f);
    rk[tid]  = r;
    tot[tid] = s * r * r;   // ||v_k||^2 * r^2 contribution to global norm
  }
  __syncthreads();
  if (tid == 0) {
    float t = 0.f;
    for (int i = 0; i < 64; ++i) t += tot[i];
    gsh = 1.f / fmaxf(sqrtf(t), 1e-12f);
  }
  __syncthreads();
  const float sc = rk[k] * gsh;
  float* op = outg + ((size_t)n * KK + k) * DD + part * 64;
#pragma unroll
  for (int j0 = 0; j0 < 64; j0 += 4) {
    f32x4 o;
#pragma unroll
    for (int jj = 0; jj < 4; ++jj) o[jj] = v[j0 + jj] * sc;
    *(f32x4*)(op + j0) = o;
  }
}

extern "C" void kernel_launch(void* const* d_in, const int* in_sizes, int n_in,
                              void* d_out, int out_size, void* d_ws, size_t ws_size,
                              hipStream_t stream) {
  const float* x   = (const float*)d_in[0];  // [64,256,64,64] fp32
  const float* wgt = (const float*)d_in[1];  // [64,256] fp32
  const float* cen = (const float*)d_in[2];  // [64,256] fp32
  float* out = (float*)d_out;                // [64, 64*256] fp32

  float* S = (float*)d_ws;                    // [N,K,D] fp32 accumulator (4 MB)
  float* A = S + (size_t)NN * KK * DD;        // [N,K] fp32 (16 KB)

  const int n4 = (NN * KK * DD + NN * KK) / 4;  // float4 count to zero
  hipLaunchKernelGGL(zero_ws_kernel, dim3((n4 + 255) / 256), dim3(256), 0, stream, S, n4);
  hipLaunchKernelGGL(netvlad_main, dim3(NN * 4), dim3(256), 0, stream, x, wgt, S, A);
  hipLaunchKernelGGL(netvlad_fin, dim3(NN), dim3(256), 0, stream, S, A, cen, out);
}